// Round 2
// baseline (594.193 us; speedup 1.0000x reference)
//
#include <hip/hip_runtime.h>
#include <math.h>

typedef __attribute__((ext_vector_type(8))) short short8;
typedef __attribute__((ext_vector_type(4))) float floatx4;

#define TB 16
#define TS 512
#define TD 768
#define TH 12
#define TDH 64
#define TNCH 3

#define SCALE 0.03608439182435161f  // 1/sqrt(768)

#define LDA_S 40   // ushort stride: 32 k + 8 pad
#define LDB_S 36   // ushort stride: 32 k + 4 pad

__device__ __forceinline__ unsigned short f2bf(float f) {
  unsigned u = __float_as_uint(f);
  u += 0x7fffu + ((u >> 16) & 1u);   // round-to-nearest-even
  return (unsigned short)(u >> 16);
}
__device__ __forceinline__ unsigned f2bf2(float lo, float hi) {
  return (unsigned)f2bf(lo) | ((unsigned)f2bf(hi) << 16);
}

union U4 { uint4 u; short8 s; };

// ===================== prep kernels (one-shot convert/transpose) ============
// pconv: fp32 -> bf16, contiguous, 8 els/thread
__global__ __launch_bounds__(256)
void pconv(const float* __restrict__ src, unsigned short* __restrict__ dst) {
  const int i = (blockIdx.x * 256 + threadIdx.x) * 8;
  const float4 a = *(const float4*)&src[i];
  const float4 b = *(const float4*)&src[i + 4];
  uint4 o;
  o.x = f2bf2(a.x, a.y); o.y = f2bf2(a.z, a.w);
  o.z = f2bf2(b.x, b.y); o.w = f2bf2(b.z, b.w);
  *(uint4*)&dst[i] = o;
}

// ptrans: per-z src [R][C] f32 -> dst [C][R] bf16 (32x32 LDS tiles)
__global__ __launch_bounds__(256)
void ptrans(const float* __restrict__ src, unsigned short* __restrict__ dst,
            int R, int C) {
  __shared__ float ts[32][33];
  const size_t zoff = (size_t)blockIdx.z * R * C;
  src += zoff; dst += zoff;
  const int c0 = blockIdx.x * 32, r0 = blockIdx.y * 32;
  const int x = threadIdx.x & 31, y = threadIdx.x >> 5;   // y in [0,8)
#pragma unroll
  for (int i = 0; i < 4; i++)
    ts[y + 8 * i][x] = src[(size_t)(r0 + y + 8 * i) * C + c0 + x];
  __syncthreads();
#pragma unroll
  for (int i = 0; i < 4; i++)
    dst[(size_t)(c0 + y + 8 * i) * R + r0 + x] = f2bf(ts[x][y + 8 * i]);
}

// ---- unified bf16 tile stage: src row-major [rows][ld], 128x32 tile ----
template <int DS>
__device__ __forceinline__ void stage_bf16(const unsigned short* __restrict__ S, int ld,
                                           int row0, int k0, int tid,
                                           unsigned short* D) {
#pragma unroll
  for (int i = 0; i < 2; i++) {
    const int idx = tid + i * 256;          // 0..511 : 128 rows x 4 chunks of 8
    const int r = idx >> 2, g = idx & 3;
    const uint4 v = *(const uint4*)&S[(size_t)(row0 + r) * ld + k0 + g * 8];
    *(uint4*)&D[r * DS + g * 8] = v;
  }
}

__device__ __forceinline__ void mfma_step(const unsigned short* As, const unsigned short* Bs,
                                          int wy, int wx, int l16, int quad,
                                          floatx4 acc[4][4]) {
  short8 af[4], bfr[4];
#pragma unroll
  for (int i = 0; i < 4; i++) {
    U4 t; t.u = *(const uint4*)&As[(wy * 64 + i * 16 + l16) * LDA_S + quad * 8];
    af[i] = t.s;
  }
#pragma unroll
  for (int j = 0; j < 4; j++) {
    const unsigned short* bp = &Bs[(wx * 64 + j * 16 + l16) * LDB_S + quad * 8];
    uint2 lo = *(const uint2*)bp;
    uint2 hi = *(const uint2*)(bp + 4);
    U4 t; t.u = make_uint4(lo.x, lo.y, hi.x, hi.y);
    bfr[j] = t.s;
  }
#pragma unroll
  for (int i = 0; i < 4; i++)
#pragma unroll
    for (int j = 0; j < 4; j++)
      acc[i][j] = __builtin_amdgcn_mfma_f32_16x16x32_bf16(af[i], bfr[j], acc[i][j], 0, 0, 0);
}

// ===== K1: qk = Htb @ WqkT^T + b_qk -> Q,K (bf16), pure-bf16 staging =====
__global__ __launch_bounds__(256, 2)
void k1_qk(const unsigned short* __restrict__ Htb, const unsigned short* __restrict__ WqkT,
           const float* __restrict__ bias, unsigned short* __restrict__ Q,
           unsigned short* __restrict__ Ko) {
  __shared__ unsigned short As[128 * LDA_S];
  __shared__ unsigned short Bs[128 * LDB_S];
  const int tid = threadIdx.x;
  const int row0 = blockIdx.y * 128, col0 = blockIdx.x * 128;
  const int w = tid >> 6, lane = tid & 63;
  const int wy = w >> 1, wx = w & 1, l16 = lane & 15, quad = lane >> 4;
  floatx4 acc[4][4];
#pragma unroll
  for (int i = 0; i < 4; i++)
#pragma unroll
    for (int j = 0; j < 4; j++)
#pragma unroll
      for (int r = 0; r < 4; r++) acc[i][j][r] = 0.f;

  for (int k0 = 0; k0 < TD; k0 += 32) {
    stage_bf16<LDA_S>(Htb, TD, row0, k0, tid, As);
    stage_bf16<LDB_S>(WqkT, TD, col0, k0, tid, Bs);
    __syncthreads();
    mfma_step(As, Bs, wy, wx, l16, quad, acc);
    __syncthreads();
  }
#pragma unroll
  for (int i = 0; i < 4; i++)
#pragma unroll
    for (int j = 0; j < 4; j++) {
      const int col = col0 + wx * 64 + j * 16 + l16;
      const float bs = bias[col];
#pragma unroll
      for (int r = 0; r < 4; r++) {
        const int row = row0 + wy * 64 + i * 16 + quad * 4 + r;
        const float v = acc[i][j][r] + bs;
        if (col < TD) Q[(size_t)row * TD + col] = f2bf(v);
        else          Ko[(size_t)row * TD + (col - TD)] = f2bf(v);
      }
    }
}

// ==== K2: MFMA scores from global bf16 frags; softmax + channel weights ====
// R7: 512 threads / 8 waves per block (64 k-cols per wave) -> 16 waves/CU.
//     Epilogue numerator M re-read from Ml in fp32 (R0 numerics, exactly).
#define OB_S 520
__global__ __launch_bounds__(512, 4)
void k2_attn(const unsigned short* __restrict__ Q, const unsigned short* __restrict__ Kb,
             const float* __restrict__ Ml, const float* __restrict__ am,
             unsigned short* __restrict__ Am) {
  __shared__ float smx[16][8];
  __shared__ float4 szd[16][8];
  __shared__ unsigned short obuf[16 * OB_S];
  const int i0 = blockIdx.x;
  const int xcd = i0 & 7, jj = i0 >> 3;
  const int b = xcd + 8 * (jj & 1);
  const int q0 = (jj >> 1) * 16;
  const int tid = threadIdx.x;
  const int w = tid >> 6, lane = tid & 63;
  const int l16 = lane & 15, quad = lane >> 4;
  const int kbase = w * 64;

  const float* amb = am + b * TS;
  float amq[4], amk[4], maskv[4];
#pragma unroll
  for (int r = 0; r < 4; r++) amq[r] = amb[q0 + quad * 4 + r];
#pragma unroll
  for (int kt = 0; kt < 4; kt++) {
    amk[kt] = amb[kbase + kt * 16 + l16];
    maskv[kt] = (1.f - amk[kt]) * (-1e9f);
  }

  unsigned Mpk[TNCH][4][2];
#pragma unroll
  for (int i = 0; i < TNCH; i++)
#pragma unroll
    for (int r = 0; r < 4; r++) {
      const float* Mrow = Ml + ((size_t)((b * TNCH + i) * TS + q0 + quad * 4 + r)) * TS;
#pragma unroll
      for (int kt2 = 0; kt2 < 2; kt2++) {
        const int ke = kbase + kt2 * 32 + l16;
        const float me = Mrow[ke] * amk[kt2 * 2] * amq[r];
        const float mo = Mrow[ke + 16] * amk[kt2 * 2 + 1] * amq[r];
        Mpk[i][r][kt2] = f2bf2(me, mo);
      }
    }

  float acc[TNCH][4][4];
#pragma unroll
  for (int i = 0; i < TNCH; i++)
#pragma unroll
    for (int kt = 0; kt < 4; kt++)
#pragma unroll
      for (int r = 0; r < 4; r++) acc[i][kt][r] = 0.f;

  const unsigned short* qbase = Q + ((size_t)(b * TS + q0 + l16)) * TD + quad * 8;
  const unsigned short* kb0   = Kb + ((size_t)(b * TS + kbase + l16)) * TD + quad * 8;

  for (int h = 0; h < TH; h++) {
    floatx4 sacc[4];
#pragma unroll
    for (int kt = 0; kt < 4; kt++)
#pragma unroll
      for (int r = 0; r < 4; r++) sacc[kt][r] = 0.f;
#pragma unroll
    for (int dk = 0; dk < 2; dk++) {
      U4 a; a.u = *(const uint4*)(qbase + h * TDH + dk * 32);
#pragma unroll
      for (int kt = 0; kt < 4; kt++) {
        U4 bb; bb.u = *(const uint4*)(kb0 + (size_t)kt * 16 * TD + h * TDH + dk * 32);
        sacc[kt] = __builtin_amdgcn_mfma_f32_16x16x32_bf16(a.s, bb.s, sacc[kt], 0, 0, 0);
      }
    }
    float s[4][4];
#pragma unroll
    for (int kt = 0; kt < 4; kt++)
#pragma unroll
      for (int r = 0; r < 4; r++) s[kt][r] = sacc[kt][r] * SCALE + maskv[kt];

    float mxp[4];
#pragma unroll
    for (int r = 0; r < 4; r++) {
      float m = s[0][r];
#pragma unroll
      for (int kt = 1; kt < 4; kt++) m = fmaxf(m, s[kt][r]);
#pragma unroll
      for (int off = 1; off < 16; off <<= 1) m = fmaxf(m, __shfl_xor(m, off));
      mxp[r] = m;
    }
    if (l16 == 0) {
#pragma unroll
      for (int r = 0; r < 4; r++) smx[quad * 4 + r][w] = mxp[r];
    }
    __syncthreads();
    float mxg[4];
#pragma unroll
    for (int r = 0; r < 4; r++) {
      const float4 t0 = *(const float4*)&smx[quad * 4 + r][0];
      const float4 t1 = *(const float4*)&smx[quad * 4 + r][4];
      mxg[r] = fmaxf(fmaxf(fmaxf(t0.x, t0.y), fmaxf(t0.z, t0.w)),
                     fmaxf(fmaxf(t1.x, t1.y), fmaxf(t1.z, t1.w)));
    }

    float Zp[4] = {0.f, 0.f, 0.f, 0.f};
#pragma unroll
    for (int kt = 0; kt < 4; kt++)
#pragma unroll
      for (int r = 0; r < 4; r++) {
        float e = __expf(s[kt][r] - mxg[r]);
        s[kt][r] = e;
        Zp[r] += e;
      }
    float dmp[TNCH][4];
#pragma unroll
    for (int i = 0; i < TNCH; i++)
#pragma unroll
      for (int r = 0; r < 4; r++) {
        float d = 0.f;
#pragma unroll
        for (int kt2 = 0; kt2 < 2; kt2++) {
          unsigned u = Mpk[i][r][kt2];
          d += __uint_as_float(u << 16) * s[kt2 * 2][r];
          d += __uint_as_float(u & 0xffff0000u) * s[kt2 * 2 + 1][r];
        }
        dmp[i][r] = d;
      }
#pragma unroll
    for (int r = 0; r < 4; r++) {
#pragma unroll
      for (int off = 1; off < 16; off <<= 1) {
        Zp[r] += __shfl_xor(Zp[r], off);
        dmp[0][r] += __shfl_xor(dmp[0][r], off);
        dmp[1][r] += __shfl_xor(dmp[1][r], off);
        dmp[2][r] += __shfl_xor(dmp[2][r], off);
      }
    }
    if (l16 == 0) {
#pragma unroll
      for (int r = 0; r < 4; r++)
        szd[quad * 4 + r][w] = make_float4(Zp[r], dmp[0][r], dmp[1][r], dmp[2][r]);
    }
    __syncthreads();
#pragma unroll
    for (int r = 0; r < 4; r++) {
      float Z = 0.f, d0 = 0.f, d1 = 0.f, d2 = 0.f;
#pragma unroll
      for (int ww = 0; ww < 8; ww++) {
        const float4 t = szd[quad * 4 + r][ww];
        Z += t.x; d0 += t.y; d1 += t.z; d2 += t.w;
      }
      const float w0 = 1.f / (d0 + 1e-10f * Z);
      const float w1 = 1.f / (d1 + 1e-10f * Z);
      const float w2 = 1.f / (d2 + 1e-10f * Z);
#pragma unroll
      for (int kt = 0; kt < 4; kt++) {
        acc[0][kt][r] += s[kt][r] * w0;
        acc[1][kt][r] += s[kt][r] * w1;
        acc[2][kt][r] += s[kt][r] * w2;
      }
    }
  }

  const float inv_h = 1.f / (float)TH;
  for (int i = 0; i < TNCH; i++) {
#pragma unroll
    for (int r = 0; r < 4; r++) {
      const int q = q0 + quad * 4 + r;
      const float* Mrow = Ml + ((size_t)((b * TNCH + i) * TS + q)) * TS;
#pragma unroll
      for (int kt = 0; kt < 4; kt++) {
        const int k = kbase + kt * 16 + l16;
        const float mv = Mrow[k] * amk[kt] * amq[r];
        obuf[(quad * 4 + r) * OB_S + k] = f2bf(mv * acc[i][kt][r] * inv_h);
      }
    }
    __syncthreads();
#pragma unroll
    for (int it = 0; it < 2; it++) {
      const int idx = tid + it * 512;
      const int row = idx >> 6, c16 = idx & 63;
      const uint4 v = *(const uint4*)&obuf[row * OB_S + c16 * 8];
      *(uint4*)&Am[((size_t)((i * TB + b) * TS + q0 + row)) * TS + c16 * 8] = v;
    }
    __syncthreads();
  }
}

// ===== K3: G[z] = Am[z] @ HtbT[b]^T -> bf16, pure-bf16 staging =====
__global__ __launch_bounds__(256, 2)
void k3_feat(const unsigned short* __restrict__ Am, const unsigned short* __restrict__ HtbT,
             unsigned short* __restrict__ G) {
  __shared__ unsigned short As[128 * LDA_S];
  __shared__ unsigned short Bs[128 * LDB_S];
  const int z = blockIdx.z;
  const int b = z & 15;
  const unsigned short* A  = Am + (size_t)z * TS * TS;
  const unsigned short* Bt = HtbT + (size_t)b * TD * TS;
  unsigned short* C = G + (size_t)z * TS * TD;
  const int tid = threadIdx.x;
  const int row0 = blockIdx.y * 128, col0 = blockIdx.x * 128;
  const int w = tid >> 6, lane = tid & 63;
  const int wy = w >> 1, wx = w & 1, l16 = lane & 15, quad = lane >> 4;
  floatx4 acc[4][4];
#pragma unroll
  for (int i = 0; i < 4; i++)
#pragma unroll
    for (int j = 0; j < 4; j++)
#pragma unroll
      for (int r = 0; r < 4; r++) acc[i][j][r] = 0.f;

  for (int k0 = 0; k0 < TS; k0 += 32) {
    stage_bf16<LDA_S>(A, TS, row0, k0, tid, As);
    stage_bf16<LDB_S>(Bt, TS, col0, k0, tid, Bs);
    __syncthreads();
    mfma_step(As, Bs, wy, wx, l16, quad, acc);
    __syncthreads();
  }
#pragma unroll
  for (int i = 0; i < 4; i++)
#pragma unroll
    for (int j = 0; j < 4; j++) {
      const int col = col0 + wx * 64 + j * 16 + l16;
#pragma unroll
      for (int r = 0; r < 4; r++) {
        const int row = row0 + wy * 64 + i * 16 + quad * 4 + r;
        C[(size_t)row * TD + col] = f2bf(acc[i][j][r]);
      }
    }
}

// == K4: out = mean_ch relu(G_ch @ WgT_ch^T + bg_ch) * am, pure-bf16 staging ==
__global__ __launch_bounds__(256, 2)
void k4_out(const unsigned short* __restrict__ G, const unsigned short* __restrict__ WgT,
            const float* __restrict__ bg, const float* __restrict__ am,
            float* __restrict__ out) {
  __shared__ unsigned short As[128 * LDA_S];
  __shared__ unsigned short Bs[128 * LDB_S];
  const int tid = threadIdx.x;
  const int row0 = blockIdx.y * 128, col0 = blockIdx.x * 128;
  const int w = tid >> 6, lane = tid & 63;
  const int wy = w >> 1, wx = w & 1, l16 = lane & 15, quad = lane >> 4;
  float osum[4][4][4];
#pragma unroll
  for (int i = 0; i < 4; i++)
#pragma unroll
    for (int j = 0; j < 4; j++)
#pragma unroll
      for (int r = 0; r < 4; r++) osum[i][j][r] = 0.f;

  for (int ch = 0; ch < TNCH; ch++) {
    const unsigned short* A  = G + (size_t)ch * (TB * TS) * TD;
    const unsigned short* Bt = WgT + (size_t)ch * TD * TD;
    floatx4 acc[4][4];
#pragma unroll
    for (int i = 0; i < 4; i++)
#pragma unroll
      for (int j = 0; j < 4; j++)
#pragma unroll
        for (int r = 0; r < 4; r++) acc[i][j][r] = 0.f;

    for (int k0 = 0; k0 < TD; k0 += 32) {
      stage_bf16<LDA_S>(A, TD, row0, k0, tid, As);
      stage_bf16<LDB_S>(Bt, TD, col0, k0, tid, Bs);
      __syncthreads();
      mfma_step(As, Bs, wy, wx, l16, quad, acc);
      __syncthreads();
    }
#pragma unroll
    for (int i = 0; i < 4; i++)
#pragma unroll
      for (int j = 0; j < 4; j++) {
        const int col = col0 + wx * 64 + j * 16 + l16;
        const float bs = bg[ch * TD + col];
#pragma unroll
        for (int r = 0; r < 4; r++)
          osum[i][j][r] += fmaxf(acc[i][j][r] + bs, 0.f);
      }
  }
#pragma unroll
  for (int i = 0; i < 4; i++)
#pragma unroll
    for (int r = 0; r < 4; r++) {
      const int row = row0 + wy * 64 + i * 16 + quad * 4 + r;
      const float amr = am[row] * (1.f / 3.f);
#pragma unroll
      for (int j = 0; j < 4; j++) {
        const int col = col0 + wx * 64 + j * 16 + l16;
        out[(size_t)row * TD + col] = osum[i][j][r] * amr;
      }
    }
}

extern "C" void kernel_launch(void* const* d_in, const int* in_sizes, int n_in,
                              void* d_out, int out_size, void* d_ws, size_t ws_size,
                              hipStream_t stream) {
  const float* Ht    = (const float*)d_in[0];
  const float* Ml    = (const float*)d_in[1];
  const float* am    = (const float*)d_in[2];
  const float* W_qk  = (const float*)d_in[3];
  const float* b_qk  = (const float*)d_in[4];
  const float* W_gat = (const float*)d_in[5];
  const float* b_gat = (const float*)d_in[6];
  float* out = (float*)d_out;

  // ws layout (ushorts):
  //   Q     [0,          6291456)
  //   K     [6291456,   12582912)
  //   Htb   [12582912,  18874368)   bf16(Ht), A-operand for k1
  //   HtbT  [18874368,  25165824)   per-b [768][512], B-operand for k3
  //   WqkT  [25165824,  26345472)   [1536][768]
  //   WgT   [26345472,  28114944)   [3][768][768]
  //   Am    [28114944,  40697856)
  //   G     [0,         18874368)   overlays Q/K/Htb (dead after k2/k1)
  unsigned short* base = (unsigned short*)d_ws;
  const size_t SEG = (size_t)TB * TS * TD;            // 6291456
  unsigned short* Q    = base;
  unsigned short* Kw   = base + SEG;
  unsigned short* Htb  = base + 2 * SEG;
  unsigned short* HtbT = base + 3 * SEG;
  unsigned short* WqkT = base + 4 * SEG;
  unsigned short* WgT  = WqkT + (size_t)TD * 2 * TD;
  unsigned short* Am   = WgT + (size_t)TNCH * TD * TD;
  unsigned short* G    = base;

  // prep: bf16 conversions + transposes (one-shot, ~100 MB traffic)
  pconv <<<dim3(3072), 256, 0, stream>>>(Ht, Htb);
  ptrans<<<dim3(24, 16, 16), 256, 0, stream>>>(Ht, HtbT, TS, TD);
  ptrans<<<dim3(48, 24, 1),  256, 0, stream>>>(W_qk, WqkT, TD, 2 * TD);
  ptrans<<<dim3(24, 24, 3),  256, 0, stream>>>(W_gat, WgT, TD, TD);

  k1_qk  <<<dim3(12, 64), 256, 0, stream>>>(Htb, WqkT, b_qk, Q, Kw);
  k2_attn<<<dim3(512), 512, 0, stream>>>(Q, Kw, Ml, am, Am);
  k3_feat<<<dim3(6, 4, 48), 256, 0, stream>>>(Am, HtbT, G);
  k4_out <<<dim3(6, 64), 256, 0, stream>>>(G, WgT, b_gat, am, out);
}

// Round 3
// 496.327 us; speedup vs baseline: 1.1972x; 1.1972x over previous
//
#include <hip/hip_runtime.h>
#include <math.h>

typedef __attribute__((ext_vector_type(8))) short short8;
typedef __attribute__((ext_vector_type(4))) float floatx4;

#define TB 16
#define TS 512
#define TD 768
#define TH 12
#define TDH 64
#define TNCH 3

#define SCALE 0.03608439182435161f  // 1/sqrt(768)

#define LDA_S 40   // ushort stride: 32 k + 8 pad
#define LDB_S 36   // ushort stride: 32 k + 4 pad

__device__ __forceinline__ unsigned short f2bf(float f) {
  unsigned u = __float_as_uint(f);
  u += 0x7fffu + ((u >> 16) & 1u);   // round-to-nearest-even
  return (unsigned short)(u >> 16);
}
__device__ __forceinline__ unsigned f2bf2(float lo, float hi) {
  return (unsigned)f2bf(lo) | ((unsigned)f2bf(hi) << 16);
}

union U4 { uint4 u; short8 s; };

// ===================== prep kernels (one-shot convert/transpose) ============
// pconv: fp32 -> bf16, contiguous, 8 els/thread
__global__ __launch_bounds__(256)
void pconv(const float* __restrict__ src, unsigned short* __restrict__ dst) {
  const int i = (blockIdx.x * 256 + threadIdx.x) * 8;
  const float4 a = *(const float4*)&src[i];
  const float4 b = *(const float4*)&src[i + 4];
  uint4 o;
  o.x = f2bf2(a.x, a.y); o.y = f2bf2(a.z, a.w);
  o.z = f2bf2(b.x, b.y); o.w = f2bf2(b.z, b.w);
  *(uint4*)&dst[i] = o;
}

// ptrans: per-z src [R][C] f32 -> dst [C][R] bf16 (32x32 LDS tiles)
__global__ __launch_bounds__(256)
void ptrans(const float* __restrict__ src, unsigned short* __restrict__ dst,
            int R, int C) {
  __shared__ float ts[32][33];
  const size_t zoff = (size_t)blockIdx.z * R * C;
  src += zoff; dst += zoff;
  const int c0 = blockIdx.x * 32, r0 = blockIdx.y * 32;
  const int x = threadIdx.x & 31, y = threadIdx.x >> 5;   // y in [0,8)
#pragma unroll
  for (int i = 0; i < 4; i++)
    ts[y + 8 * i][x] = src[(size_t)(r0 + y + 8 * i) * C + c0 + x];
  __syncthreads();
#pragma unroll
  for (int i = 0; i < 4; i++)
    dst[(size_t)(c0 + y + 8 * i) * R + r0 + x] = f2bf(ts[x][y + 8 * i]);
}

// ---- unified bf16 tile stage: src row-major [rows][ld], 128x32 tile ----
template <int DS>
__device__ __forceinline__ void stage_bf16(const unsigned short* __restrict__ S, int ld,
                                           int row0, int k0, int tid,
                                           unsigned short* D) {
#pragma unroll
  for (int i = 0; i < 2; i++) {
    const int idx = tid + i * 256;          // 0..511 : 128 rows x 4 chunks of 8
    const int r = idx >> 2, g = idx & 3;
    const uint4 v = *(const uint4*)&S[(size_t)(row0 + r) * ld + k0 + g * 8];
    *(uint4*)&D[r * DS + g * 8] = v;
  }
}

__device__ __forceinline__ void mfma_step(const unsigned short* As, const unsigned short* Bs,
                                          int wy, int wx, int l16, int quad,
                                          floatx4 acc[4][4]) {
  short8 af[4], bfr[4];
#pragma unroll
  for (int i = 0; i < 4; i++) {
    U4 t; t.u = *(const uint4*)&As[(wy * 64 + i * 16 + l16) * LDA_S + quad * 8];
    af[i] = t.s;
  }
#pragma unroll
  for (int j = 0; j < 4; j++) {
    const unsigned short* bp = &Bs[(wx * 64 + j * 16 + l16) * LDB_S + quad * 8];
    uint2 lo = *(const uint2*)bp;
    uint2 hi = *(const uint2*)(bp + 4);
    U4 t; t.u = make_uint4(lo.x, lo.y, hi.x, hi.y);
    bfr[j] = t.s;
  }
#pragma unroll
  for (int i = 0; i < 4; i++)
#pragma unroll
    for (int j = 0; j < 4; j++)
      acc[i][j] = __builtin_amdgcn_mfma_f32_16x16x32_bf16(af[i], bfr[j], acc[i][j], 0, 0, 0);
}

// ===== K1: qk = Htb @ WqkT^T + b_qk -> Q,K (bf16), pure-bf16 staging =====
__global__ __launch_bounds__(256, 2)
void k1_qk(const unsigned short* __restrict__ Htb, const unsigned short* __restrict__ WqkT,
           const float* __restrict__ bias, unsigned short* __restrict__ Q,
           unsigned short* __restrict__ Ko) {
  __shared__ unsigned short As[128 * LDA_S];
  __shared__ unsigned short Bs[128 * LDB_S];
  const int tid = threadIdx.x;
  const int row0 = blockIdx.y * 128, col0 = blockIdx.x * 128;
  const int w = tid >> 6, lane = tid & 63;
  const int wy = w >> 1, wx = w & 1, l16 = lane & 15, quad = lane >> 4;
  floatx4 acc[4][4];
#pragma unroll
  for (int i = 0; i < 4; i++)
#pragma unroll
    for (int j = 0; j < 4; j++)
#pragma unroll
      for (int r = 0; r < 4; r++) acc[i][j][r] = 0.f;

  for (int k0 = 0; k0 < TD; k0 += 32) {
    stage_bf16<LDA_S>(Htb, TD, row0, k0, tid, As);
    stage_bf16<LDB_S>(WqkT, TD, col0, k0, tid, Bs);
    __syncthreads();
    mfma_step(As, Bs, wy, wx, l16, quad, acc);
    __syncthreads();
  }
#pragma unroll
  for (int i = 0; i < 4; i++)
#pragma unroll
    for (int j = 0; j < 4; j++) {
      const int col = col0 + wx * 64 + j * 16 + l16;
      const float bs = bias[col];
#pragma unroll
      for (int r = 0; r < 4; r++) {
        const int row = row0 + wy * 64 + i * 16 + quad * 4 + r;
        const float v = acc[i][j][r] + bs;
        if (col < TD) Q[(size_t)row * TD + col] = f2bf(v);
        else          Ko[(size_t)row * TD + (col - TD)] = f2bf(v);
      }
    }
}

// ==== K2: MFMA scores from global bf16 frags; softmax + channel weights ====
// R8: back to R0 structure (256 thr / 4 waves / 128 k-cols per wave).
//     NEW: two heads per reduction round -> 2x load MLP, barriers 24 -> 12.
//     Per-head numerics identical to R0 (same max/sum order, fp32 epilogue M).
#define OB_S 520
__global__ __launch_bounds__(256, 2)
void k2_attn(const unsigned short* __restrict__ Q, const unsigned short* __restrict__ Kb,
             const float* __restrict__ Ml, const float* __restrict__ am,
             unsigned short* __restrict__ Am) {
  __shared__ float smx[2][16][4];
  __shared__ float4 szd[2][16][4];
  __shared__ unsigned short obuf[16 * OB_S];
  const int i0 = blockIdx.x;
  const int xcd = i0 & 7, jj = i0 >> 3;
  const int b = xcd + 8 * (jj & 1);
  const int q0 = (jj >> 1) * 16;
  const int tid = threadIdx.x;
  const int w = tid >> 6, lane = tid & 63;
  const int l16 = lane & 15, quad = lane >> 4;
  const int kbase = w * 128;

  const float* amb = am + b * TS;
  float amq[4], amk[8], maskv[8];
#pragma unroll
  for (int r = 0; r < 4; r++) amq[r] = amb[q0 + quad * 4 + r];
#pragma unroll
  for (int kt = 0; kt < 8; kt++) {
    amk[kt] = amb[kbase + kt * 16 + l16];
    maskv[kt] = (1.f - amk[kt]) * (-1e9f);
  }

  unsigned Mpk[TNCH][4][4];
#pragma unroll
  for (int i = 0; i < TNCH; i++)
#pragma unroll
    for (int r = 0; r < 4; r++) {
      const float* Mrow = Ml + ((size_t)((b * TNCH + i) * TS + q0 + quad * 4 + r)) * TS;
#pragma unroll
      for (int kt2 = 0; kt2 < 4; kt2++) {
        const int ke = kbase + kt2 * 32 + l16;
        const float me = Mrow[ke] * amk[kt2 * 2] * amq[r];
        const float mo = Mrow[ke + 16] * amk[kt2 * 2 + 1] * amq[r];
        Mpk[i][r][kt2] = f2bf2(me, mo);
      }
    }

  float acc[TNCH][8][4];
#pragma unroll
  for (int i = 0; i < TNCH; i++)
#pragma unroll
    for (int kt = 0; kt < 8; kt++)
#pragma unroll
      for (int r = 0; r < 4; r++) acc[i][kt][r] = 0.f;

  const unsigned short* qbase = Q + ((size_t)(b * TS + q0 + l16)) * TD + quad * 8;
  const unsigned short* kb0   = Kb + ((size_t)(b * TS + kbase + l16)) * TD + quad * 8;

  for (int hp = 0; hp < TH; hp += 2) {
    // ---- scores for both heads (loads for h0 and h1 in flight together) ----
    floatx4 sacc[2][8];
#pragma unroll
    for (int hh = 0; hh < 2; hh++)
#pragma unroll
      for (int kt = 0; kt < 8; kt++)
#pragma unroll
        for (int r = 0; r < 4; r++) sacc[hh][kt][r] = 0.f;
#pragma unroll
    for (int dk = 0; dk < 2; dk++) {
      U4 a0; a0.u = *(const uint4*)(qbase + hp * TDH + dk * 32);
      U4 a1; a1.u = *(const uint4*)(qbase + (hp + 1) * TDH + dk * 32);
#pragma unroll
      for (int kt = 0; kt < 8; kt++) {
        const unsigned short* kp = kb0 + (size_t)kt * 16 * TD + hp * TDH + dk * 32;
        U4 b0; b0.u = *(const uint4*)kp;
        U4 b1; b1.u = *(const uint4*)(kp + TDH);
        sacc[0][kt] = __builtin_amdgcn_mfma_f32_16x16x32_bf16(a0.s, b0.s, sacc[0][kt], 0, 0, 0);
        sacc[1][kt] = __builtin_amdgcn_mfma_f32_16x16x32_bf16(a1.s, b1.s, sacc[1][kt], 0, 0, 0);
      }
    }
    float s[2][8][4];
#pragma unroll
    for (int hh = 0; hh < 2; hh++)
#pragma unroll
      for (int kt = 0; kt < 8; kt++)
#pragma unroll
        for (int r = 0; r < 4; r++) s[hh][kt][r] = sacc[hh][kt][r] * SCALE + maskv[kt];

    // ---- per-wave max for both heads, one barrier ----
#pragma unroll
    for (int hh = 0; hh < 2; hh++) {
      float mxp[4];
#pragma unroll
      for (int r = 0; r < 4; r++) {
        float m = s[hh][0][r];
#pragma unroll
        for (int kt = 1; kt < 8; kt++) m = fmaxf(m, s[hh][kt][r]);
#pragma unroll
        for (int off = 1; off < 16; off <<= 1) m = fmaxf(m, __shfl_xor(m, off));
        mxp[r] = m;
      }
      if (l16 == 0) {
#pragma unroll
        for (int r = 0; r < 4; r++) smx[hh][quad * 4 + r][w] = mxp[r];
      }
    }
    __syncthreads();
    float mxg[2][4];
#pragma unroll
    for (int hh = 0; hh < 2; hh++)
#pragma unroll
      for (int r = 0; r < 4; r++) {
        float4 t = *(const float4*)smx[hh][quad * 4 + r];
        mxg[hh][r] = fmaxf(fmaxf(t.x, t.y), fmaxf(t.z, t.w));
      }

    // ---- exp + partial Z and per-channel denominators, both heads ----
    float Zp[2][4];
    float dmp[2][TNCH][4];
#pragma unroll
    for (int hh = 0; hh < 2; hh++) {
#pragma unroll
      for (int r = 0; r < 4; r++) Zp[hh][r] = 0.f;
#pragma unroll
      for (int kt = 0; kt < 8; kt++)
#pragma unroll
        for (int r = 0; r < 4; r++) {
          float e = __expf(s[hh][kt][r] - mxg[hh][r]);
          s[hh][kt][r] = e;
          Zp[hh][r] += e;
        }
#pragma unroll
      for (int i = 0; i < TNCH; i++)
#pragma unroll
        for (int r = 0; r < 4; r++) {
          float d = 0.f;
#pragma unroll
          for (int kt2 = 0; kt2 < 4; kt2++) {
            unsigned u = Mpk[i][r][kt2];
            d += __uint_as_float(u << 16) * s[hh][kt2 * 2][r];
            d += __uint_as_float(u & 0xffff0000u) * s[hh][kt2 * 2 + 1][r];
          }
          dmp[hh][i][r] = d;
        }
    }
#pragma unroll
    for (int r = 0; r < 4; r++) {
#pragma unroll
      for (int off = 1; off < 16; off <<= 1) {
#pragma unroll
        for (int hh = 0; hh < 2; hh++) {
          Zp[hh][r] += __shfl_xor(Zp[hh][r], off);
          dmp[hh][0][r] += __shfl_xor(dmp[hh][0][r], off);
          dmp[hh][1][r] += __shfl_xor(dmp[hh][1][r], off);
          dmp[hh][2][r] += __shfl_xor(dmp[hh][2][r], off);
        }
      }
    }
    if (l16 == 0) {
#pragma unroll
      for (int hh = 0; hh < 2; hh++)
#pragma unroll
        for (int r = 0; r < 4; r++)
          szd[hh][quad * 4 + r][w] =
              make_float4(Zp[hh][r], dmp[hh][0][r], dmp[hh][1][r], dmp[hh][2][r]);
    }
    __syncthreads();
#pragma unroll
    for (int hh = 0; hh < 2; hh++) {
#pragma unroll
      for (int r = 0; r < 4; r++) {
        float4 t0 = szd[hh][quad * 4 + r][0];
        float4 t1 = szd[hh][quad * 4 + r][1];
        float4 t2 = szd[hh][quad * 4 + r][2];
        float4 t3 = szd[hh][quad * 4 + r][3];
        const float Z  = t0.x + t1.x + t2.x + t3.x;
        const float w0 = 1.f / (t0.y + t1.y + t2.y + t3.y + 1e-10f * Z);
        const float w1 = 1.f / (t0.z + t1.z + t2.z + t3.z + 1e-10f * Z);
        const float w2 = 1.f / (t0.w + t1.w + t2.w + t3.w + 1e-10f * Z);
#pragma unroll
        for (int kt = 0; kt < 8; kt++) {
          acc[0][kt][r] += s[hh][kt][r] * w0;
          acc[1][kt][r] += s[hh][kt][r] * w1;
          acc[2][kt][r] += s[hh][kt][r] * w2;
        }
      }
    }
  }

  const float inv_h = 1.f / (float)TH;
  for (int i = 0; i < TNCH; i++) {
#pragma unroll
    for (int r = 0; r < 4; r++) {
      const int q = q0 + quad * 4 + r;
      const float* Mrow = Ml + ((size_t)((b * TNCH + i) * TS + q)) * TS;
#pragma unroll
      for (int kt = 0; kt < 8; kt++) {
        const int k = kbase + kt * 16 + l16;
        const float mv = Mrow[k] * amk[kt] * amq[r];
        obuf[(quad * 4 + r) * OB_S + k] = f2bf(mv * acc[i][kt][r] * inv_h);
      }
    }
    __syncthreads();
#pragma unroll
    for (int it = 0; it < 4; it++) {
      const int idx = tid + it * 256;
      const int row = idx >> 6, c16 = idx & 63;
      const uint4 v = *(const uint4*)&obuf[row * OB_S + c16 * 8];
      *(uint4*)&Am[((size_t)((i * TB + b) * TS + q0 + row)) * TS + c16 * 8] = v;
    }
    __syncthreads();
  }
}

// ===== K3: G[z] = Am[z] @ HtbT[b]^T -> bf16, pure-bf16 staging =====
__global__ __launch_bounds__(256, 2)
void k3_feat(const unsigned short* __restrict__ Am, const unsigned short* __restrict__ HtbT,
             unsigned short* __restrict__ G) {
  __shared__ unsigned short As[128 * LDA_S];
  __shared__ unsigned short Bs[128 * LDB_S];
  const int z = blockIdx.z;
  const int b = z & 15;
  const unsigned short* A  = Am + (size_t)z * TS * TS;
  const unsigned short* Bt = HtbT + (size_t)b * TD * TS;
  unsigned short* C = G + (size_t)z * TS * TD;
  const int tid = threadIdx.x;
  const int row0 = blockIdx.y * 128, col0 = blockIdx.x * 128;
  const int w = tid >> 6, lane = tid & 63;
  const int wy = w >> 1, wx = w & 1, l16 = lane & 15, quad = lane >> 4;
  floatx4 acc[4][4];
#pragma unroll
  for (int i = 0; i < 4; i++)
#pragma unroll
    for (int j = 0; j < 4; j++)
#pragma unroll
      for (int r = 0; r < 4; r++) acc[i][j][r] = 0.f;

  for (int k0 = 0; k0 < TS; k0 += 32) {
    stage_bf16<LDA_S>(A, TS, row0, k0, tid, As);
    stage_bf16<LDB_S>(Bt, TS, col0, k0, tid, Bs);
    __syncthreads();
    mfma_step(As, Bs, wy, wx, l16, quad, acc);
    __syncthreads();
  }
#pragma unroll
  for (int i = 0; i < 4; i++)
#pragma unroll
    for (int j = 0; j < 4; j++) {
      const int col = col0 + wx * 64 + j * 16 + l16;
#pragma unroll
      for (int r = 0; r < 4; r++) {
        const int row = row0 + wy * 64 + i * 16 + quad * 4 + r;
        C[(size_t)row * TD + col] = f2bf(acc[i][j][r]);
      }
    }
}

// == K4: out = mean_ch relu(G_ch @ WgT_ch^T + bg_ch) * am, pure-bf16 staging ==
__global__ __launch_bounds__(256, 2)
void k4_out(const unsigned short* __restrict__ G, const unsigned short* __restrict__ WgT,
            const float* __restrict__ bg, const float* __restrict__ am,
            float* __restrict__ out) {
  __shared__ unsigned short As[128 * LDA_S];
  __shared__ unsigned short Bs[128 * LDB_S];
  const int tid = threadIdx.x;
  const int row0 = blockIdx.y * 128, col0 = blockIdx.x * 128;
  const int w = tid >> 6, lane = tid & 63;
  const int wy = w >> 1, wx = w & 1, l16 = lane & 15, quad = lane >> 4;
  float osum[4][4][4];
#pragma unroll
  for (int i = 0; i < 4; i++)
#pragma unroll
    for (int j = 0; j < 4; j++)
#pragma unroll
      for (int r = 0; r < 4; r++) osum[i][j][r] = 0.f;

  for (int ch = 0; ch < TNCH; ch++) {
    const unsigned short* A  = G + (size_t)ch * (TB * TS) * TD;
    const unsigned short* Bt = WgT + (size_t)ch * TD * TD;
    floatx4 acc[4][4];
#pragma unroll
    for (int i = 0; i < 4; i++)
#pragma unroll
      for (int j = 0; j < 4; j++)
#pragma unroll
        for (int r = 0; r < 4; r++) acc[i][j][r] = 0.f;

    for (int k0 = 0; k0 < TD; k0 += 32) {
      stage_bf16<LDA_S>(A, TD, row0, k0, tid, As);
      stage_bf16<LDB_S>(Bt, TD, col0, k0, tid, Bs);
      __syncthreads();
      mfma_step(As, Bs, wy, wx, l16, quad, acc);
      __syncthreads();
    }
#pragma unroll
    for (int i = 0; i < 4; i++)
#pragma unroll
      for (int j = 0; j < 4; j++) {
        const int col = col0 + wx * 64 + j * 16 + l16;
        const float bs = bg[ch * TD + col];
#pragma unroll
        for (int r = 0; r < 4; r++)
          osum[i][j][r] += fmaxf(acc[i][j][r] + bs, 0.f);
      }
  }
#pragma unroll
  for (int i = 0; i < 4; i++)
#pragma unroll
    for (int r = 0; r < 4; r++) {
      const int row = row0 + wy * 64 + i * 16 + quad * 4 + r;
      const float amr = am[row] * (1.f / 3.f);
#pragma unroll
      for (int j = 0; j < 4; j++) {
        const int col = col0 + wx * 64 + j * 16 + l16;
        out[(size_t)row * TD + col] = osum[i][j][r] * amr;
      }
    }
}

extern "C" void kernel_launch(void* const* d_in, const int* in_sizes, int n_in,
                              void* d_out, int out_size, void* d_ws, size_t ws_size,
                              hipStream_t stream) {
  const float* Ht    = (const float*)d_in[0];
  const float* Ml    = (const float*)d_in[1];
  const float* am    = (const float*)d_in[2];
  const float* W_qk  = (const float*)d_in[3];
  const float* b_qk  = (const float*)d_in[4];
  const float* W_gat = (const float*)d_in[5];
  const float* b_gat = (const float*)d_in[6];
  float* out = (float*)d_out;

  // ws layout (ushorts):
  //   Q     [0,          6291456)
  //   K     [6291456,   12582912)
  //   Htb   [12582912,  18874368)   bf16(Ht), A-operand for k1
  //   HtbT  [18874368,  25165824)   per-b [768][512], B-operand for k3
  //   WqkT  [25165824,  26345472)   [1536][768]
  //   WgT   [26345472,  28114944)   [3][768][768]
  //   Am    [28114944,  40697856)
  //   G     [0,         18874368)   overlays Q/K/Htb (dead after k2/k1)
  unsigned short* base = (unsigned short*)d_ws;
  const size_t SEG = (size_t)TB * TS * TD;            // 6291456
  unsigned short* Q    = base;
  unsigned short* Kw   = base + SEG;
  unsigned short* Htb  = base + 2 * SEG;
  unsigned short* HtbT = base + 3 * SEG;
  unsigned short* WqkT = base + 4 * SEG;
  unsigned short* WgT  = WqkT + (size_t)TD * 2 * TD;
  unsigned short* Am   = WgT + (size_t)TNCH * TD * TD;
  unsigned short* G    = base;

  // prep: bf16 conversions + transposes (one-shot, ~100 MB traffic)
  pconv <<<dim3(3072), 256, 0, stream>>>(Ht, Htb);
  ptrans<<<dim3(24, 16, 16), 256, 0, stream>>>(Ht, HtbT, TS, TD);
  ptrans<<<dim3(48, 24, 1),  256, 0, stream>>>(W_qk, WqkT, TD, 2 * TD);
  ptrans<<<dim3(24, 24, 3),  256, 0, stream>>>(W_gat, WgT, TD, TD);

  k1_qk  <<<dim3(12, 64), 256, 0, stream>>>(Htb, WqkT, b_qk, Q, Kw);
  k2_attn<<<dim3(512), 256, 0, stream>>>(Q, Kw, Ml, am, Am);
  k3_feat<<<dim3(6, 4, 48), 256, 0, stream>>>(Am, HtbT, G);
  k4_out <<<dim3(6, 64), 256, 0, stream>>>(G, WgT, b_gat, am, out);
}

// Round 5
// 424.409 us; speedup vs baseline: 1.4000x; 1.1695x over previous
//
#include <hip/hip_runtime.h>
#include <math.h>

typedef __attribute__((ext_vector_type(8))) short short8;
typedef __attribute__((ext_vector_type(4))) float floatx4;

#define TB 16
#define TS 512
#define TD 768
#define TH 12
#define TDH 64
#define TNCH 3

#define SCALE 0.03608439182435161f  // 1/sqrt(768)

#define LDA_S 40   // ushort stride: 32 k + 8 pad
#define LDB_S 36   // ushort stride: 32 k + 4 pad

__device__ __forceinline__ unsigned short f2bf(float f) {
  unsigned u = __float_as_uint(f);
  u += 0x7fffu + ((u >> 16) & 1u);   // round-to-nearest-even
  return (unsigned short)(u >> 16);
}
__device__ __forceinline__ unsigned f2bf2(float lo, float hi) {
  return (unsigned)f2bf(lo) | ((unsigned)f2bf(hi) << 16);
}

union U4 { uint4 u; short8 s; };

// ===================== prep kernels (one-shot convert/transpose) ============
// pconv: fp32 -> bf16, contiguous, 8 els/thread
__global__ __launch_bounds__(256)
void pconv(const float* __restrict__ src, unsigned short* __restrict__ dst) {
  const int i = (blockIdx.x * 256 + threadIdx.x) * 8;
  const float4 a = *(const float4*)&src[i];
  const float4 b = *(const float4*)&src[i + 4];
  uint4 o;
  o.x = f2bf2(a.x, a.y); o.y = f2bf2(a.z, a.w);
  o.z = f2bf2(b.x, b.y); o.w = f2bf2(b.z, b.w);
  *(uint4*)&dst[i] = o;
}

// ptrans: per-z src [R][C] f32 -> dst [C][R] bf16 (32x32 LDS tiles)
__global__ __launch_bounds__(256)
void ptrans(const float* __restrict__ src, unsigned short* __restrict__ dst,
            int R, int C) {
  __shared__ float ts[32][33];
  const size_t zoff = (size_t)blockIdx.z * R * C;
  src += zoff; dst += zoff;
  const int c0 = blockIdx.x * 32, r0 = blockIdx.y * 32;
  const int x = threadIdx.x & 31, y = threadIdx.x >> 5;   // y in [0,8)
#pragma unroll
  for (int i = 0; i < 4; i++)
    ts[y + 8 * i][x] = src[(size_t)(r0 + y + 8 * i) * C + c0 + x];
  __syncthreads();
#pragma unroll
  for (int i = 0; i < 4; i++)
    dst[(size_t)(c0 + y + 8 * i) * R + r0 + x] = f2bf(ts[x][y + 8 * i]);
}

// ---- unified bf16 tile stage: src row-major [rows][ld], 128x32 tile ----
template <int DS>
__device__ __forceinline__ void stage_bf16(const unsigned short* __restrict__ S, int ld,
                                           int row0, int k0, int tid,
                                           unsigned short* D) {
#pragma unroll
  for (int i = 0; i < 2; i++) {
    const int idx = tid + i * 256;          // 0..511 : 128 rows x 4 chunks of 8
    const int r = idx >> 2, g = idx & 3;
    const uint4 v = *(const uint4*)&S[(size_t)(row0 + r) * ld + k0 + g * 8];
    *(uint4*)&D[r * DS + g * 8] = v;
  }
}

__device__ __forceinline__ void mfma_step(const unsigned short* As, const unsigned short* Bs,
                                          int wy, int wx, int l16, int quad,
                                          floatx4 acc[4][4]) {
  short8 af[4], bfr[4];
#pragma unroll
  for (int i = 0; i < 4; i++) {
    U4 t; t.u = *(const uint4*)&As[(wy * 64 + i * 16 + l16) * LDA_S + quad * 8];
    af[i] = t.s;
  }
#pragma unroll
  for (int j = 0; j < 4; j++) {
    const unsigned short* bp = &Bs[(wx * 64 + j * 16 + l16) * LDB_S + quad * 8];
    uint2 lo = *(const uint2*)bp;
    uint2 hi = *(const uint2*)(bp + 4);
    U4 t; t.u = make_uint4(lo.x, lo.y, hi.x, hi.y);
    bfr[j] = t.s;
  }
#pragma unroll
  for (int i = 0; i < 4; i++)
#pragma unroll
    for (int j = 0; j < 4; j++)
      acc[i][j] = __builtin_amdgcn_mfma_f32_16x16x32_bf16(af[i], bfr[j], acc[i][j], 0, 0, 0);
}

// ===== K1: qk = Htb @ WqkT^T + b_qk -> Q,K (bf16), pure-bf16 staging =====
__global__ __launch_bounds__(256, 2)
void k1_qk(const unsigned short* __restrict__ Htb, const unsigned short* __restrict__ WqkT,
           const float* __restrict__ bias, unsigned short* __restrict__ Q,
           unsigned short* __restrict__ Ko) {
  __shared__ unsigned short As[128 * LDA_S];
  __shared__ unsigned short Bs[128 * LDB_S];
  const int tid = threadIdx.x;
  const int row0 = blockIdx.y * 128, col0 = blockIdx.x * 128;
  const int w = tid >> 6, lane = tid & 63;
  const int wy = w >> 1, wx = w & 1, l16 = lane & 15, quad = lane >> 4;
  floatx4 acc[4][4];
#pragma unroll
  for (int i = 0; i < 4; i++)
#pragma unroll
    for (int j = 0; j < 4; j++)
#pragma unroll
      for (int r = 0; r < 4; r++) acc[i][j][r] = 0.f;

  for (int k0 = 0; k0 < TD; k0 += 32) {
    stage_bf16<LDA_S>(Htb, TD, row0, k0, tid, As);
    stage_bf16<LDB_S>(WqkT, TD, col0, k0, tid, Bs);
    __syncthreads();
    mfma_step(As, Bs, wy, wx, l16, quad, acc);
    __syncthreads();
  }
#pragma unroll
  for (int i = 0; i < 4; i++)
#pragma unroll
    for (int j = 0; j < 4; j++) {
      const int col = col0 + wx * 64 + j * 16 + l16;
      const float bs = bias[col];
#pragma unroll
      for (int r = 0; r < 4; r++) {
        const int row = row0 + wy * 64 + i * 16 + quad * 4 + r;
        const float v = acc[i][j][r] + bs;
        if (col < TD) Q[(size_t)row * TD + col] = f2bf(v);
        else          Ko[(size_t)row * TD + (col - TD)] = f2bf(v);
      }
    }
}

// ==== K2: MFMA scores; no-max-sub two-pass softmax (barrier-free passes) ====
// R9: A = M*e/(sum M*e + eps) is invariant to max-subtraction, so drop it.
//     Pass 1: scores->exp->per-wave d-partials->LDS (no acc regs, no barriers).
//     One barrier; reduce partials -> w[12][16][3] in LDS. One barrier.
//     Pass 2: re-MFMA scores (MFMA util ~1%, recompute free; K hits L2),
//     exp (bit-identical), acc += e*w. No per-head barriers anywhere.
#define OB_S 520
__global__ __launch_bounds__(256, 2)
void k2_attn(const unsigned short* __restrict__ Q, const unsigned short* __restrict__ Kb,
             const float* __restrict__ Ml, const float* __restrict__ am,
             unsigned short* __restrict__ Am) {
  // LDS plan (1040 float4 = 16640 B):
  //   [0, 768)   part[h][q][wave] float4 {Z,d0,d1,d2}   (pass 1)
  //   [768, 960) wlds[h][q] float4 {w0,w1,w2,-}         (pass 2)
  //   epilogue: obuf (16*OB_S ushorts = 16640 B) overlays everything
  __shared__ float4 ldsf4[1040];
  const int i0 = blockIdx.x;
  const int xcd = i0 & 7, jj = i0 >> 3;
  const int b = xcd + 8 * (jj & 1);
  const int q0 = (jj >> 1) * 16;
  const int tid = threadIdx.x;
  const int w = tid >> 6, lane = tid & 63;
  const int l16 = lane & 15, quad = lane >> 4;
  const int kbase = w * 128;

  const float* amb = am + b * TS;
  float amq[4], amk[8], maskv[8];
#pragma unroll
  for (int r = 0; r < 4; r++) amq[r] = amb[q0 + quad * 4 + r];
#pragma unroll
  for (int kt = 0; kt < 8; kt++) {
    amk[kt] = amb[kbase + kt * 16 + l16];
    maskv[kt] = (1.f - amk[kt]) * (-1e9f);
  }

  unsigned Mpk[TNCH][4][4];
#pragma unroll
  for (int i = 0; i < TNCH; i++)
#pragma unroll
    for (int r = 0; r < 4; r++) {
      const float* Mrow = Ml + ((size_t)((b * TNCH + i) * TS + q0 + quad * 4 + r)) * TS;
#pragma unroll
      for (int kt2 = 0; kt2 < 4; kt2++) {
        const int ke = kbase + kt2 * 32 + l16;
        const float me = Mrow[ke] * amk[kt2 * 2] * amq[r];
        const float mo = Mrow[ke + 16] * amk[kt2 * 2 + 1] * amq[r];
        Mpk[i][r][kt2] = f2bf2(me, mo);
      }
    }

  const unsigned short* qbase = Q + ((size_t)(b * TS + q0 + l16)) * TD + quad * 8;
  const unsigned short* kb0   = Kb + ((size_t)(b * TS + kbase + l16)) * TD + quad * 8;

  // ---------------- pass 1: denominators only (barrier-free loop) ----------
  for (int h = 0; h < TH; h++) {
    floatx4 sacc[8];
#pragma unroll
    for (int kt = 0; kt < 8; kt++)
#pragma unroll
      for (int r = 0; r < 4; r++) sacc[kt][r] = 0.f;
#pragma unroll
    for (int dk = 0; dk < 2; dk++) {
      U4 a; a.u = *(const uint4*)(qbase + h * TDH + dk * 32);
#pragma unroll
      for (int kt = 0; kt < 8; kt++) {
        U4 bb; bb.u = *(const uint4*)(kb0 + (size_t)kt * 16 * TD + h * TDH + dk * 32);
        sacc[kt] = __builtin_amdgcn_mfma_f32_16x16x32_bf16(a.s, bb.s, sacc[kt], 0, 0, 0);
      }
    }
    float e[8][4];
    float Zp[4] = {0.f, 0.f, 0.f, 0.f};
#pragma unroll
    for (int kt = 0; kt < 8; kt++)
#pragma unroll
      for (int r = 0; r < 4; r++) {
        const float v = __expf(sacc[kt][r] * SCALE + maskv[kt]);
        e[kt][r] = v;
        Zp[r] += v;
      }
    float dmp[TNCH][4];
#pragma unroll
    for (int i = 0; i < TNCH; i++)
#pragma unroll
      for (int r = 0; r < 4; r++) {
        float d = 0.f;
#pragma unroll
        for (int kt2 = 0; kt2 < 4; kt2++) {
          const unsigned u = Mpk[i][r][kt2];
          d += __uint_as_float(u << 16) * e[kt2 * 2][r];
          d += __uint_as_float(u & 0xffff0000u) * e[kt2 * 2 + 1][r];
        }
        dmp[i][r] = d;
      }
#pragma unroll
    for (int r = 0; r < 4; r++) {
#pragma unroll
      for (int off = 1; off < 16; off <<= 1) {
        Zp[r] += __shfl_xor(Zp[r], off);
        dmp[0][r] += __shfl_xor(dmp[0][r], off);
        dmp[1][r] += __shfl_xor(dmp[1][r], off);
        dmp[2][r] += __shfl_xor(dmp[2][r], off);
      }
    }
    if (l16 == 0) {
#pragma unroll
      for (int r = 0; r < 4; r++)
        ldsf4[(h * 16 + quad * 4 + r) * 4 + w] =
            make_float4(Zp[r], dmp[0][r], dmp[1][r], dmp[2][r]);
    }
  }
  __syncthreads();

  // ---------------- reduce partials -> per-(h,q) channel weights -----------
  if (tid < TH * 16) {
    const int h = tid >> 4, q = tid & 15;
    const int base = (h * 16 + q) * 4;
    const float4 p0 = ldsf4[base + 0];
    const float4 p1 = ldsf4[base + 1];
    const float4 p2 = ldsf4[base + 2];
    const float4 p3 = ldsf4[base + 3];
    const float Z  = p0.x + p1.x + p2.x + p3.x;
    const float d0 = p0.y + p1.y + p2.y + p3.y;
    const float d1 = p0.z + p1.z + p2.z + p3.z;
    const float d2 = p0.w + p1.w + p2.w + p3.w;
    const float ez = 1e-10f * Z + 1e-30f;
    ldsf4[768 + h * 16 + q] =
        make_float4(1.f / (d0 + ez), 1.f / (d1 + ez), 1.f / (d2 + ez), 0.f);
  }
  __syncthreads();

  // ---------------- pass 2: recompute e, accumulate (barrier-free loop) ----
  float acc[TNCH][8][4];
#pragma unroll
  for (int i = 0; i < TNCH; i++)
#pragma unroll
    for (int kt = 0; kt < 8; kt++)
#pragma unroll
      for (int r = 0; r < 4; r++) acc[i][kt][r] = 0.f;

  for (int h = 0; h < TH; h++) {
    floatx4 sacc[8];
#pragma unroll
    for (int kt = 0; kt < 8; kt++)
#pragma unroll
      for (int r = 0; r < 4; r++) sacc[kt][r] = 0.f;
#pragma unroll
    for (int dk = 0; dk < 2; dk++) {
      U4 a; a.u = *(const uint4*)(qbase + h * TDH + dk * 32);
#pragma unroll
      for (int kt = 0; kt < 8; kt++) {
        U4 bb; bb.u = *(const uint4*)(kb0 + (size_t)kt * 16 * TD + h * TDH + dk * 32);
        sacc[kt] = __builtin_amdgcn_mfma_f32_16x16x32_bf16(a.s, bb.s, sacc[kt], 0, 0, 0);
      }
    }
    float4 wv[4];
#pragma unroll
    for (int r = 0; r < 4; r++) wv[r] = ldsf4[768 + h * 16 + quad * 4 + r];
#pragma unroll
    for (int kt = 0; kt < 8; kt++)
#pragma unroll
      for (int r = 0; r < 4; r++) {
        const float v = __expf(sacc[kt][r] * SCALE + maskv[kt]);
        acc[0][kt][r] += v * wv[r].x;
        acc[1][kt][r] += v * wv[r].y;
        acc[2][kt][r] += v * wv[r].z;
      }
  }
  __syncthreads();   // protect obuf overlay of part/wlds

  // ---------------- epilogue: Am = bf16(M * acc / 12), staged via LDS ------
  unsigned short* obuf = (unsigned short*)ldsf4;
  const float inv_h = 1.f / (float)TH;
  for (int i = 0; i < TNCH; i++) {
#pragma unroll
    for (int r = 0; r < 4; r++) {
      const int q = q0 + quad * 4 + r;
      const float* Mrow = Ml + ((size_t)((b * TNCH + i) * TS + q)) * TS;
#pragma unroll
      for (int kt = 0; kt < 8; kt++) {
        const int k = kbase + kt * 16 + l16;
        const float mv = Mrow[k] * amk[kt] * amq[r];
        obuf[(quad * 4 + r) * OB_S + k] = f2bf(mv * acc[i][kt][r] * inv_h);
      }
    }
    __syncthreads();
#pragma unroll
    for (int it = 0; it < 4; it++) {
      const int idx = tid + it * 256;
      const int row = idx >> 6, c16 = idx & 63;
      const uint4 v = *(const uint4*)&obuf[row * OB_S + c16 * 8];
      *(uint4*)&Am[((size_t)((i * TB + b) * TS + q0 + row)) * TS + c16 * 8] = v;
    }
    __syncthreads();
  }
}

// ===== K3: G[z] = Am[z] @ HtbT[b]^T -> bf16, pure-bf16 staging =====
__global__ __launch_bounds__(256, 2)
void k3_feat(const unsigned short* __restrict__ Am, const unsigned short* __restrict__ HtbT,
             unsigned short* __restrict__ G) {
  __shared__ unsigned short As[128 * LDA_S];
  __shared__ unsigned short Bs[128 * LDB_S];
  const int z = blockIdx.z;
  const int b = z & 15;
  const unsigned short* A  = Am + (size_t)z * TS * TS;
  const unsigned short* Bt = HtbT + (size_t)b * TD * TS;
  unsigned short* C = G + (size_t)z * TS * TD;
  const int tid = threadIdx.x;
  const int row0 = blockIdx.y * 128, col0 = blockIdx.x * 128;
  const int w = tid >> 6, lane = tid & 63;
  const int wy = w >> 1, wx = w & 1, l16 = lane & 15, quad = lane >> 4;
  floatx4 acc[4][4];
#pragma unroll
  for (int i = 0; i < 4; i++)
#pragma unroll
    for (int j = 0; j < 4; j++)
#pragma unroll
      for (int r = 0; r < 4; r++) acc[i][j][r] = 0.f;

  for (int k0 = 0; k0 < TS; k0 += 32) {
    stage_bf16<LDA_S>(A, TS, row0, k0, tid, As);
    stage_bf16<LDB_S>(Bt, TS, col0, k0, tid, Bs);
    __syncthreads();
    mfma_step(As, Bs, wy, wx, l16, quad, acc);
    __syncthreads();
  }
#pragma unroll
  for (int i = 0; i < 4; i++)
#pragma unroll
    for (int j = 0; j < 4; j++) {
      const int col = col0 + wx * 64 + j * 16 + l16;
#pragma unroll
      for (int r = 0; r < 4; r++) {
        const int row = row0 + wy * 64 + i * 16 + quad * 4 + r;
        C[(size_t)row * TD + col] = f2bf(acc[i][j][r]);
      }
    }
}

// == K4: out = mean_ch relu(G_ch @ WgT_ch^T + bg_ch) * am, pure-bf16 staging ==
__global__ __launch_bounds__(256, 2)
void k4_out(const unsigned short* __restrict__ G, const unsigned short* __restrict__ WgT,
            const float* __restrict__ bg, const float* __restrict__ am,
            float* __restrict__ out) {
  __shared__ unsigned short As[128 * LDA_S];
  __shared__ unsigned short Bs[128 * LDB_S];
  const int tid = threadIdx.x;
  const int row0 = blockIdx.y * 128, col0 = blockIdx.x * 128;
  const int w = tid >> 6, lane = tid & 63;
  const int wy = w >> 1, wx = w & 1, l16 = lane & 15, quad = lane >> 4;
  float osum[4][4][4];
#pragma unroll
  for (int i = 0; i < 4; i++)
#pragma unroll
    for (int j = 0; j < 4; j++)
#pragma unroll
      for (int r = 0; r < 4; r++) osum[i][j][r] = 0.f;

  for (int ch = 0; ch < TNCH; ch++) {
    const unsigned short* A  = G + (size_t)ch * (TB * TS) * TD;
    const unsigned short* Bt = WgT + (size_t)ch * TD * TD;
    floatx4 acc[4][4];
#pragma unroll
    for (int i = 0; i < 4; i++)
#pragma unroll
      for (int j = 0; j < 4; j++)
#pragma unroll
        for (int r = 0; r < 4; r++) acc[i][j][r] = 0.f;

    for (int k0 = 0; k0 < TD; k0 += 32) {
      stage_bf16<LDA_S>(A, TD, row0, k0, tid, As);
      stage_bf16<LDB_S>(Bt, TD, col0, k0, tid, Bs);
      __syncthreads();
      mfma_step(As, Bs, wy, wx, l16, quad, acc);
      __syncthreads();
    }
#pragma unroll
    for (int i = 0; i < 4; i++)
#pragma unroll
      for (int j = 0; j < 4; j++) {
        const int col = col0 + wx * 64 + j * 16 + l16;
        const float bs = bg[ch * TD + col];
#pragma unroll
        for (int r = 0; r < 4; r++)
          osum[i][j][r] += fmaxf(acc[i][j][r] + bs, 0.f);
      }
  }
#pragma unroll
  for (int i = 0; i < 4; i++)
#pragma unroll
    for (int r = 0; r < 4; r++) {
      const int row = row0 + wy * 64 + i * 16 + quad * 4 + r;
      const float amr = am[row] * (1.f / 3.f);
#pragma unroll
      for (int j = 0; j < 4; j++) {
        const int col = col0 + wx * 64 + j * 16 + l16;
        out[(size_t)row * TD + col] = osum[i][j][r] * amr;
      }
    }
}

extern "C" void kernel_launch(void* const* d_in, const int* in_sizes, int n_in,
                              void* d_out, int out_size, void* d_ws, size_t ws_size,
                              hipStream_t stream) {
  const float* Ht    = (const float*)d_in[0];
  const float* Ml    = (const float*)d_in[1];
  const float* am    = (const float*)d_in[2];
  const float* W_qk  = (const float*)d_in[3];
  const float* b_qk  = (const float*)d_in[4];
  const float* W_gat = (const float*)d_in[5];
  const float* b_gat = (const float*)d_in[6];
  float* out = (float*)d_out;

  // ws layout (ushorts):
  //   Q     [0,          6291456)
  //   K     [6291456,   12582912)
  //   Htb   [12582912,  18874368)   bf16(Ht), A-operand for k1
  //   HtbT  [18874368,  25165824)   per-b [768][512], B-operand for k3
  //   WqkT  [25165824,  26345472)   [1536][768]
  //   WgT   [26345472,  28114944)   [3][768][768]
  //   Am    [28114944,  40697856)
  //   G     [0,         18874368)   overlays Q/K/Htb (dead after k2/k1)
  unsigned short* base = (unsigned short*)d_ws;
  const size_t SEG = (size_t)TB * TS * TD;            // 6291456
  unsigned short* Q    = base;
  unsigned short* Kw   = base + SEG;
  unsigned short* Htb  = base + 2 * SEG;
  unsigned short* HtbT = base + 3 * SEG;
  unsigned short* WqkT = base + 4 * SEG;
  unsigned short* WgT  = WqkT + (size_t)TD * 2 * TD;
  unsigned short* Am   = WgT + (size_t)TNCH * TD * TD;
  unsigned short* G    = base;

  // prep: bf16 conversions + transposes (one-shot, ~100 MB traffic)
  pconv <<<dim3(3072), 256, 0, stream>>>(Ht, Htb);
  ptrans<<<dim3(24, 16, 16), 256, 0, stream>>>(Ht, HtbT, TS, TD);
  ptrans<<<dim3(48, 24, 1),  256, 0, stream>>>(W_qk, WqkT, TD, 2 * TD);
  ptrans<<<dim3(24, 24, 3),  256, 0, stream>>>(W_gat, WgT, TD, TD);

  k1_qk  <<<dim3(12, 64), 256, 0, stream>>>(Htb, WqkT, b_qk, Q, Kw);
  k2_attn<<<dim3(512), 256, 0, stream>>>(Q, Kw, Ml, am, Am);
  k3_feat<<<dim3(6, 4, 48), 256, 0, stream>>>(Am, HtbT, G);
  k4_out <<<dim3(6, 64), 256, 0, stream>>>(G, WgT, b_gat, am, out);
}

// Round 6
// 378.808 us; speedup vs baseline: 1.5686x; 1.1204x over previous
//
#include <hip/hip_runtime.h>
#include <math.h>

typedef __attribute__((ext_vector_type(8))) short short8;
typedef __attribute__((ext_vector_type(4))) float floatx4;

#define TB 16
#define TS 512
#define TD 768
#define TH 12
#define TDH 64
#define TNCH 3

#define SCALE 0.03608439182435161f  // 1/sqrt(768)

__device__ __forceinline__ unsigned short f2bf(float f) {
  unsigned u = __float_as_uint(f);
  u += 0x7fffu + ((u >> 16) & 1u);   // round-to-nearest-even
  return (unsigned short)(u >> 16);
}
__device__ __forceinline__ unsigned f2bf2(float lo, float hi) {
  return (unsigned)f2bf(lo) | ((unsigned)f2bf(hi) << 16);
}

union U4 { uint4 u; short8 s; };

// ===================== prep kernels (one-shot convert/transpose) ============
// pconv: fp32 -> bf16, contiguous, 8 els/thread
__global__ __launch_bounds__(256)
void pconv(const float* __restrict__ src, unsigned short* __restrict__ dst) {
  const int i = (blockIdx.x * 256 + threadIdx.x) * 8;
  const float4 a = *(const float4*)&src[i];
  const float4 b = *(const float4*)&src[i + 4];
  uint4 o;
  o.x = f2bf2(a.x, a.y); o.y = f2bf2(a.z, a.w);
  o.z = f2bf2(b.x, b.y); o.w = f2bf2(b.z, b.w);
  *(uint4*)&dst[i] = o;
}

// ptrans: per-z src [R][C] f32 -> dst [C][R] bf16 (32x32 LDS tiles)
__global__ __launch_bounds__(256)
void ptrans(const float* __restrict__ src, unsigned short* __restrict__ dst,
            int R, int C) {
  __shared__ float ts[32][33];
  const size_t zoff = (size_t)blockIdx.z * R * C;
  src += zoff; dst += zoff;
  const int c0 = blockIdx.x * 32, r0 = blockIdx.y * 32;
  const int x = threadIdx.x & 31, y = threadIdx.x >> 5;   // y in [0,8)
#pragma unroll
  for (int i = 0; i < 4; i++)
    ts[y + 8 * i][x] = src[(size_t)(r0 + y + 8 * i) * C + c0 + x];
  __syncthreads();
#pragma unroll
  for (int i = 0; i < 4; i++)
    dst[(size_t)(c0 + y + 8 * i) * R + r0 + x] = f2bf(ts[x][y + 8 * i]);
}

// ---- R10 GEMM staging: async global->LDS, width 16, linear [128][32] ------
// m97 recipe: LDS dest is wave-uniform base; lane l lands at base + l*16 B
// (row = base_row + l/4, 16B chunk = l&3). No padding allowed (linear).
__device__ __forceinline__ void stage_gll(const unsigned short* __restrict__ S, int ld,
                                          int row0, int k0, int w, int lane,
                                          unsigned short* D) {
  const int rsub = lane >> 2, c = lane & 3;
#pragma unroll
  for (int i = 0; i < 2; i++) {
    const int r = w * 32 + i * 16;
    const unsigned short* g = &S[(size_t)(row0 + r + rsub) * ld + k0 + c * 8];
    unsigned short* d = &D[r * 32];
    __builtin_amdgcn_global_load_lds(
        (const __attribute__((address_space(1))) unsigned int*)(const void*)g,
        (__attribute__((address_space(3))) unsigned int*)(void*)d,
        16, 0, 0);
  }
}

__device__ __forceinline__ void mfma_step_lin(const unsigned short* As, const unsigned short* Bs,
                                              int wy, int wx, int l16, int quad,
                                              floatx4 acc[4][4]) {
  short8 af[4], bfr[4];
#pragma unroll
  for (int i = 0; i < 4; i++) {
    U4 t; t.u = *(const uint4*)&As[(wy * 64 + i * 16 + l16) * 32 + quad * 8];
    af[i] = t.s;
  }
#pragma unroll
  for (int j = 0; j < 4; j++) {
    U4 t; t.u = *(const uint4*)&Bs[(wx * 64 + j * 16 + l16) * 32 + quad * 8];
    bfr[j] = t.s;
  }
#pragma unroll
  for (int i = 0; i < 4; i++)
#pragma unroll
    for (int j = 0; j < 4; j++)
      acc[i][j] = __builtin_amdgcn_mfma_f32_16x16x32_bf16(af[i], bfr[j], acc[i][j], 0, 0, 0);
}

// ===== K1: qk = Htb @ WqkT^T + b_qk -> Q,K (bf16), async-LDS staging =====
__global__ __launch_bounds__(256, 2)
void k1_qk(const unsigned short* __restrict__ Htb, const unsigned short* __restrict__ WqkT,
           const float* __restrict__ bias, unsigned short* __restrict__ Q,
           unsigned short* __restrict__ Ko) {
  __shared__ unsigned short As[128 * 32];
  __shared__ unsigned short Bs[128 * 32];
  const int tid = threadIdx.x;
  const int row0 = blockIdx.y * 128, col0 = blockIdx.x * 128;
  const int w = tid >> 6, lane = tid & 63;
  const int wy = w >> 1, wx = w & 1, l16 = lane & 15, quad = lane >> 4;
  floatx4 acc[4][4];
#pragma unroll
  for (int i = 0; i < 4; i++)
#pragma unroll
    for (int j = 0; j < 4; j++)
#pragma unroll
      for (int r = 0; r < 4; r++) acc[i][j][r] = 0.f;

  for (int k0 = 0; k0 < TD; k0 += 32) {
    stage_gll(Htb, TD, row0, k0, w, lane, As);
    stage_gll(WqkT, TD, col0, k0, w, lane, Bs);
    __syncthreads();
    mfma_step_lin(As, Bs, wy, wx, l16, quad, acc);
    __syncthreads();
  }
#pragma unroll
  for (int i = 0; i < 4; i++)
#pragma unroll
    for (int j = 0; j < 4; j++) {
      const int col = col0 + wx * 64 + j * 16 + l16;
      const float bs = bias[col];
#pragma unroll
      for (int r = 0; r < 4; r++) {
        const int row = row0 + wy * 64 + i * 16 + quad * 4 + r;
        const float v = acc[i][j][r] + bs;
        if (col < TD) Q[(size_t)row * TD + col] = f2bf(v);
        else          Ko[(size_t)row * TD + (col - TD)] = f2bf(v);
      }
    }
}

// ==== K2: MFMA scores; no-max-sub two-pass softmax (barrier-free passes) ====
// R9 (verified 128 us): A = M*e/(sum M*e + eps) is max-invariant -> drop max.
#define OB_S 520
__global__ __launch_bounds__(256, 2)
void k2_attn(const unsigned short* __restrict__ Q, const unsigned short* __restrict__ Kb,
             const float* __restrict__ Ml, const float* __restrict__ am,
             unsigned short* __restrict__ Am) {
  // LDS plan (1040 float4 = 16640 B):
  //   [0, 768)   part[h][q][wave] float4 {Z,d0,d1,d2}   (pass 1)
  //   [768, 960) wlds[h][q] float4 {w0,w1,w2,-}         (pass 2)
  //   epilogue: obuf (16*OB_S ushorts = 16640 B) overlays everything
  __shared__ float4 ldsf4[1040];
  const int i0 = blockIdx.x;
  const int xcd = i0 & 7, jj = i0 >> 3;
  const int b = xcd + 8 * (jj & 1);
  const int q0 = (jj >> 1) * 16;
  const int tid = threadIdx.x;
  const int w = tid >> 6, lane = tid & 63;
  const int l16 = lane & 15, quad = lane >> 4;
  const int kbase = w * 128;

  const float* amb = am + b * TS;
  float amq[4], amk[8], maskv[8];
#pragma unroll
  for (int r = 0; r < 4; r++) amq[r] = amb[q0 + quad * 4 + r];
#pragma unroll
  for (int kt = 0; kt < 8; kt++) {
    amk[kt] = amb[kbase + kt * 16 + l16];
    maskv[kt] = (1.f - amk[kt]) * (-1e9f);
  }

  unsigned Mpk[TNCH][4][4];
#pragma unroll
  for (int i = 0; i < TNCH; i++)
#pragma unroll
    for (int r = 0; r < 4; r++) {
      const float* Mrow = Ml + ((size_t)((b * TNCH + i) * TS + q0 + quad * 4 + r)) * TS;
#pragma unroll
      for (int kt2 = 0; kt2 < 4; kt2++) {
        const int ke = kbase + kt2 * 32 + l16;
        const float me = Mrow[ke] * amk[kt2 * 2] * amq[r];
        const float mo = Mrow[ke + 16] * amk[kt2 * 2 + 1] * amq[r];
        Mpk[i][r][kt2] = f2bf2(me, mo);
      }
    }

  const unsigned short* qbase = Q + ((size_t)(b * TS + q0 + l16)) * TD + quad * 8;
  const unsigned short* kb0   = Kb + ((size_t)(b * TS + kbase + l16)) * TD + quad * 8;

  // ---------------- pass 1: denominators only (barrier-free loop) ----------
  for (int h = 0; h < TH; h++) {
    floatx4 sacc[8];
#pragma unroll
    for (int kt = 0; kt < 8; kt++)
#pragma unroll
      for (int r = 0; r < 4; r++) sacc[kt][r] = 0.f;
#pragma unroll
    for (int dk = 0; dk < 2; dk++) {
      U4 a; a.u = *(const uint4*)(qbase + h * TDH + dk * 32);
#pragma unroll
      for (int kt = 0; kt < 8; kt++) {
        U4 bb; bb.u = *(const uint4*)(kb0 + (size_t)kt * 16 * TD + h * TDH + dk * 32);
        sacc[kt] = __builtin_amdgcn_mfma_f32_16x16x32_bf16(a.s, bb.s, sacc[kt], 0, 0, 0);
      }
    }
    float e[8][4];
    float Zp[4] = {0.f, 0.f, 0.f, 0.f};
#pragma unroll
    for (int kt = 0; kt < 8; kt++)
#pragma unroll
      for (int r = 0; r < 4; r++) {
        const float v = __expf(sacc[kt][r] * SCALE + maskv[kt]);
        e[kt][r] = v;
        Zp[r] += v;
      }
    float dmp[TNCH][4];
#pragma unroll
    for (int i = 0; i < TNCH; i++)
#pragma unroll
      for (int r = 0; r < 4; r++) {
        float d = 0.f;
#pragma unroll
        for (int kt2 = 0; kt2 < 4; kt2++) {
          const unsigned u = Mpk[i][r][kt2];
          d += __uint_as_float(u << 16) * e[kt2 * 2][r];
          d += __uint_as_float(u & 0xffff0000u) * e[kt2 * 2 + 1][r];
        }
        dmp[i][r] = d;
      }
#pragma unroll
    for (int r = 0; r < 4; r++) {
#pragma unroll
      for (int off = 1; off < 16; off <<= 1) {
        Zp[r] += __shfl_xor(Zp[r], off);
        dmp[0][r] += __shfl_xor(dmp[0][r], off);
        dmp[1][r] += __shfl_xor(dmp[1][r], off);
        dmp[2][r] += __shfl_xor(dmp[2][r], off);
      }
    }
    if (l16 == 0) {
#pragma unroll
      for (int r = 0; r < 4; r++)
        ldsf4[(h * 16 + quad * 4 + r) * 4 + w] =
            make_float4(Zp[r], dmp[0][r], dmp[1][r], dmp[2][r]);
    }
  }
  __syncthreads();

  // ---------------- reduce partials -> per-(h,q) channel weights -----------
  if (tid < TH * 16) {
    const int h = tid >> 4, q = tid & 15;
    const int base = (h * 16 + q) * 4;
    const float4 p0 = ldsf4[base + 0];
    const float4 p1 = ldsf4[base + 1];
    const float4 p2 = ldsf4[base + 2];
    const float4 p3 = ldsf4[base + 3];
    const float Z  = p0.x + p1.x + p2.x + p3.x;
    const float d0 = p0.y + p1.y + p2.y + p3.y;
    const float d1 = p0.z + p1.z + p2.z + p3.z;
    const float d2 = p0.w + p1.w + p2.w + p3.w;
    const float ez = 1e-10f * Z + 1e-30f;
    ldsf4[768 + h * 16 + q] =
        make_float4(1.f / (d0 + ez), 1.f / (d1 + ez), 1.f / (d2 + ez), 0.f);
  }
  __syncthreads();

  // ---------------- pass 2: recompute e, accumulate (barrier-free loop) ----
  float acc[TNCH][8][4];
#pragma unroll
  for (int i = 0; i < TNCH; i++)
#pragma unroll
    for (int kt = 0; kt < 8; kt++)
#pragma unroll
      for (int r = 0; r < 4; r++) acc[i][kt][r] = 0.f;

  for (int h = 0; h < TH; h++) {
    floatx4 sacc[8];
#pragma unroll
    for (int kt = 0; kt < 8; kt++)
#pragma unroll
      for (int r = 0; r < 4; r++) sacc[kt][r] = 0.f;
#pragma unroll
    for (int dk = 0; dk < 2; dk++) {
      U4 a; a.u = *(const uint4*)(qbase + h * TDH + dk * 32);
#pragma unroll
      for (int kt = 0; kt < 8; kt++) {
        U4 bb; bb.u = *(const uint4*)(kb0 + (size_t)kt * 16 * TD + h * TDH + dk * 32);
        sacc[kt] = __builtin_amdgcn_mfma_f32_16x16x32_bf16(a.s, bb.s, sacc[kt], 0, 0, 0);
      }
    }
    float4 wv[4];
#pragma unroll
    for (int r = 0; r < 4; r++) wv[r] = ldsf4[768 + h * 16 + quad * 4 + r];
#pragma unroll
    for (int kt = 0; kt < 8; kt++)
#pragma unroll
      for (int r = 0; r < 4; r++) {
        const float v = __expf(sacc[kt][r] * SCALE + maskv[kt]);
        acc[0][kt][r] += v * wv[r].x;
        acc[1][kt][r] += v * wv[r].y;
        acc[2][kt][r] += v * wv[r].z;
      }
  }
  __syncthreads();   // protect obuf overlay of part/wlds

  // ---------------- epilogue: Am = bf16(M * acc / 12), staged via LDS ------
  unsigned short* obuf = (unsigned short*)ldsf4;
  const float inv_h = 1.f / (float)TH;
  for (int i = 0; i < TNCH; i++) {
#pragma unroll
    for (int r = 0; r < 4; r++) {
      const int q = q0 + quad * 4 + r;
      const float* Mrow = Ml + ((size_t)((b * TNCH + i) * TS + q)) * TS;
#pragma unroll
      for (int kt = 0; kt < 8; kt++) {
        const int k = kbase + kt * 16 + l16;
        const float mv = Mrow[k] * amk[kt] * amq[r];
        obuf[(quad * 4 + r) * OB_S + k] = f2bf(mv * acc[i][kt][r] * inv_h);
      }
    }
    __syncthreads();
#pragma unroll
    for (int it = 0; it < 4; it++) {
      const int idx = tid + it * 256;
      const int row = idx >> 6, c16 = idx & 63;
      const uint4 v = *(const uint4*)&obuf[row * OB_S + c16 * 8];
      *(uint4*)&Am[((size_t)((i * TB + b) * TS + q0 + row)) * TS + c16 * 8] = v;
    }
    __syncthreads();
  }
}

// ===== K3: G[z] = Am[z] @ HtbT[b]^T -> bf16, async-LDS staging =====
__global__ __launch_bounds__(256, 2)
void k3_feat(const unsigned short* __restrict__ Am, const unsigned short* __restrict__ HtbT,
             unsigned short* __restrict__ G) {
  __shared__ unsigned short As[128 * 32];
  __shared__ unsigned short Bs[128 * 32];
  const int z = blockIdx.z;
  const int b = z & 15;
  const unsigned short* A  = Am + (size_t)z * TS * TS;
  const unsigned short* Bt = HtbT + (size_t)b * TD * TS;
  unsigned short* C = G + (size_t)z * TS * TD;
  const int tid = threadIdx.x;
  const int row0 = blockIdx.y * 128, col0 = blockIdx.x * 128;
  const int w = tid >> 6, lane = tid & 63;
  const int wy = w >> 1, wx = w & 1, l16 = lane & 15, quad = lane >> 4;
  floatx4 acc[4][4];
#pragma unroll
  for (int i = 0; i < 4; i++)
#pragma unroll
    for (int j = 0; j < 4; j++)
#pragma unroll
      for (int r = 0; r < 4; r++) acc[i][j][r] = 0.f;

  for (int k0 = 0; k0 < TS; k0 += 32) {
    stage_gll(A, TS, row0, k0, w, lane, As);
    stage_gll(Bt, TS, col0, k0, w, lane, Bs);
    __syncthreads();
    mfma_step_lin(As, Bs, wy, wx, l16, quad, acc);
    __syncthreads();
  }
#pragma unroll
  for (int i = 0; i < 4; i++)
#pragma unroll
    for (int j = 0; j < 4; j++) {
      const int col = col0 + wx * 64 + j * 16 + l16;
#pragma unroll
      for (int r = 0; r < 4; r++) {
        const int row = row0 + wy * 64 + i * 16 + quad * 4 + r;
        C[(size_t)row * TD + col] = f2bf(acc[i][j][r]);
      }
    }
}

// == K4: out = mean_ch relu(G_ch @ WgT_ch^T + bg_ch) * am, async-LDS staging ==
__global__ __launch_bounds__(256, 2)
void k4_out(const unsigned short* __restrict__ G, const unsigned short* __restrict__ WgT,
            const float* __restrict__ bg, const float* __restrict__ am,
            float* __restrict__ out) {
  __shared__ unsigned short As[128 * 32];
  __shared__ unsigned short Bs[128 * 32];
  const int tid = threadIdx.x;
  const int row0 = blockIdx.y * 128, col0 = blockIdx.x * 128;
  const int w = tid >> 6, lane = tid & 63;
  const int wy = w >> 1, wx = w & 1, l16 = lane & 15, quad = lane >> 4;
  float osum[4][4][4];
#pragma unroll
  for (int i = 0; i < 4; i++)
#pragma unroll
    for (int j = 0; j < 4; j++)
#pragma unroll
      for (int r = 0; r < 4; r++) osum[i][j][r] = 0.f;

  for (int ch = 0; ch < TNCH; ch++) {
    const unsigned short* A  = G + (size_t)ch * (TB * TS) * TD;
    const unsigned short* Bt = WgT + (size_t)ch * TD * TD;
    floatx4 acc[4][4];
#pragma unroll
    for (int i = 0; i < 4; i++)
#pragma unroll
      for (int j = 0; j < 4; j++)
#pragma unroll
        for (int r = 0; r < 4; r++) acc[i][j][r] = 0.f;

    for (int k0 = 0; k0 < TD; k0 += 32) {
      stage_gll(A, TD, row0, k0, w, lane, As);
      stage_gll(Bt, TD, col0, k0, w, lane, Bs);
      __syncthreads();
      mfma_step_lin(As, Bs, wy, wx, l16, quad, acc);
      __syncthreads();
    }
#pragma unroll
    for (int i = 0; i < 4; i++)
#pragma unroll
      for (int j = 0; j < 4; j++) {
        const int col = col0 + wx * 64 + j * 16 + l16;
        const float bs = bg[ch * TD + col];
#pragma unroll
        for (int r = 0; r < 4; r++)
          osum[i][j][r] += fmaxf(acc[i][j][r] + bs, 0.f);
      }
  }
#pragma unroll
  for (int i = 0; i < 4; i++)
#pragma unroll
    for (int r = 0; r < 4; r++) {
      const int row = row0 + wy * 64 + i * 16 + quad * 4 + r;
      const float amr = am[row] * (1.f / 3.f);
#pragma unroll
      for (int j = 0; j < 4; j++) {
        const int col = col0 + wx * 64 + j * 16 + l16;
        out[(size_t)row * TD + col] = osum[i][j][r] * amr;
      }
    }
}

extern "C" void kernel_launch(void* const* d_in, const int* in_sizes, int n_in,
                              void* d_out, int out_size, void* d_ws, size_t ws_size,
                              hipStream_t stream) {
  const float* Ht    = (const float*)d_in[0];
  const float* Ml    = (const float*)d_in[1];
  const float* am    = (const float*)d_in[2];
  const float* W_qk  = (const float*)d_in[3];
  const float* b_qk  = (const float*)d_in[4];
  const float* W_gat = (const float*)d_in[5];
  const float* b_gat = (const float*)d_in[6];
  float* out = (float*)d_out;

  // ws layout (ushorts):
  //   Q     [0,          6291456)
  //   K     [6291456,   12582912)
  //   Htb   [12582912,  18874368)   bf16(Ht), A-operand for k1
  //   HtbT  [18874368,  25165824)   per-b [768][512], B-operand for k3
  //   WqkT  [25165824,  26345472)   [1536][768]
  //   WgT   [26345472,  28114944)   [3][768][768]
  //   Am    [28114944,  40697856)
  //   G     [0,         18874368)   overlays Q/K/Htb (dead after k2/k1)
  unsigned short* base = (unsigned short*)d_ws;
  const size_t SEG = (size_t)TB * TS * TD;            // 6291456
  unsigned short* Q    = base;
  unsigned short* Kw   = base + SEG;
  unsigned short* Htb  = base + 2 * SEG;
  unsigned short* HtbT = base + 3 * SEG;
  unsigned short* WqkT = base + 4 * SEG;
  unsigned short* WgT  = WqkT + (size_t)TD * 2 * TD;
  unsigned short* Am   = WgT + (size_t)TNCH * TD * TD;
  unsigned short* G    = base;

  // prep: bf16 conversions + transposes (one-shot, ~100 MB traffic)
  pconv <<<dim3(3072), 256, 0, stream>>>(Ht, Htb);
  ptrans<<<dim3(24, 16, 16), 256, 0, stream>>>(Ht, HtbT, TS, TD);
  ptrans<<<dim3(48, 24, 1),  256, 0, stream>>>(W_qk, WqkT, TD, 2 * TD);
  ptrans<<<dim3(24, 24, 3),  256, 0, stream>>>(W_gat, WgT, TD, TD);

  k1_qk  <<<dim3(12, 64), 256, 0, stream>>>(Htb, WqkT, b_qk, Q, Kw);
  k2_attn<<<dim3(512), 256, 0, stream>>>(Q, Kw, Ml, am, Am);
  k3_feat<<<dim3(6, 4, 48), 256, 0, stream>>>(Am, HtbT, G);
  k4_out <<<dim3(6, 64), 256, 0, stream>>>(G, WgT, b_gat, am, out);
}